// Round 3
// baseline (535.867 us; speedup 1.0000x reference)
//
#include <hip/hip_runtime.h>
#include <stdint.h>

typedef __attribute__((ext_vector_type(8))) short short8;
typedef __attribute__((ext_vector_type(4))) float floatx4;

#define S_LEN 2048
#define OTOT  6144
#define KOFF  4096
#define VOFF  5120

__device__ __forceinline__ unsigned short f2bf(float f) {
  unsigned int u = __float_as_uint(f);
  u += 0x7FFFu + ((u >> 16) & 1u);
  return (unsigned short)(u >> 16);
}

__device__ __forceinline__ unsigned int pack2bf(float lo, float hi) {
  unsigned int r;
  asm("v_cvt_pk_bf16_f32 %0, %1, %2" : "=v"(r) : "v"(lo), "v"(hi));
  return r;
}

__device__ __forceinline__ void gload_lds16(const void* g, void* l) {
  __builtin_amdgcn_global_load_lds(
      (const __attribute__((address_space(1))) void*)g,
      (__attribute__((address_space(3))) void*)l, 16, 0, 0);
}

// ---------------- fused fp32 -> bf16 casts (hidden, wqkv, wo) ----------------
__global__ void cast3_kernel(const float* __restrict__ ha, const float* __restrict__ wq,
                             const float* __restrict__ wo_,
                             unsigned short* __restrict__ oh,
                             unsigned short* __restrict__ owq,
                             unsigned short* __restrict__ owo) {
  int i0 = blockIdx.x * 256 + threadIdx.x;
  int stride = gridDim.x * 256;
#pragma unroll 1
  for (int i = i0; i < 2097152; i += stride) {
    float4 v = ((const float4*)ha)[i];
    ushort4 o; o.x = f2bf(v.x); o.y = f2bf(v.y); o.z = f2bf(v.z); o.w = f2bf(v.w);
    ((ushort4*)oh)[i] = o;
  }
#pragma unroll 1
  for (int i = i0; i < 6291456; i += stride) {
    float4 v = ((const float4*)wq)[i];
    ushort4 o; o.x = f2bf(v.x); o.y = f2bf(v.y); o.z = f2bf(v.z); o.w = f2bf(v.w);
    ((ushort4*)owq)[i] = o;
  }
#pragma unroll 1
  for (int i = i0; i < 4194304; i += stride) {
    float4 v = ((const float4*)wo_)[i];
    ushort4 o; o.x = f2bf(v.x); o.y = f2bf(v.y); o.z = f2bf(v.z); o.w = f2bf(v.w);
    ((ushort4*)owo)[i] = o;
  }
}

// ---------------- V transpose (LDS-tiled): vt[g*128+d][s] = qkv[s][VOFF+g*128+d]
__global__ __launch_bounds__(256) void transpose_v_kernel(
    const unsigned short* __restrict__ qkv, unsigned short* __restrict__ vt) {
  __shared__ unsigned short T[128 * 74];
  int s0 = (blockIdx.x & 31) * 64;
  int g = blockIdx.x >> 5;
  int tid = threadIdx.x;
#pragma unroll
  for (int it = 0; it < 16; ++it) {
    int idx = it * 256 + tid;
    int srow = idx >> 6;
    int dc = idx & 63;
    unsigned int v = *(const unsigned int*)&qkv[(size_t)(s0 + srow) * OTOT + VOFF + g * 128 + dc * 2];
    T[(2 * dc) * 74 + srow] = (unsigned short)(v & 0xFFFF);
    T[(2 * dc + 1) * 74 + srow] = (unsigned short)(v >> 16);
  }
  __syncthreads();
#pragma unroll
  for (int it = 0; it < 16; ++it) {
    int odx = it * 256 + tid;
    int d = odx >> 5;
    int sc2 = odx & 31;
    unsigned int w = *(const unsigned int*)&T[d * 74 + 2 * sc2];
    *(unsigned int*)&vt[(size_t)(g * 128 + d) * S_LEN + s0 + 2 * sc2] = w;
  }
}

// ---------------- GEMM: C[M,N] = A[M,K] * B[N,K]^T (both K-major bf16) ----
template <typename CT>
__global__ __launch_bounds__(256, 2) void gemm_bt_kernel(
    const unsigned short* __restrict__ A, const unsigned short* __restrict__ B,
    CT* __restrict__ C, int M, int N, int K) {
  __shared__ unsigned short As[128 * 64];
  __shared__ unsigned short Bs[128 * 64];

  int nbn = N >> 7;
  int nwg = gridDim.x;
  int bid = blockIdx.x;
  if ((nwg & 7) == 0) bid = (bid & 7) * (nwg >> 3) + (bid >> 3);
  int bm = bid / nbn, bn = bid % nbn;

  int tid = threadIdx.x;
  int lane = tid & 63, wave = tid >> 6;
  int lr = lane & 15, lh = lane >> 4;
  int wm = (wave >> 1) << 6, wn = (wave & 1) << 6;

  floatx4 acc[4][4];
#pragma unroll
  for (int i = 0; i < 4; ++i)
#pragma unroll
    for (int j = 0; j < 4; ++j) acc[i][j] = (floatx4){0.f, 0.f, 0.f, 0.f};

  const size_t arow = (size_t)bm * 128;
  const size_t brow = (size_t)bn * 128;
  int nk = K >> 6;
  for (int kt = 0; kt < nk; ++kt) {
#pragma unroll
    for (int i = 0; i < 4; ++i) {
      int lin = i * 4096 + tid * 16;
      int row = lin >> 7;
      int colb = (lin & 127) ^ ((row & 7) << 4);
      gload_lds16(&A[(arow + row) * K + kt * 64 + (colb >> 1)],
                  &As[(i * 4096 + wave * 1024) >> 1]);
    }
#pragma unroll
    for (int i = 0; i < 4; ++i) {
      int lin = i * 4096 + tid * 16;
      int row = lin >> 7;
      int colb = (lin & 127) ^ ((row & 7) << 4);
      gload_lds16(&B[(brow + row) * K + kt * 64 + (colb >> 1)],
                  &Bs[(i * 4096 + wave * 1024) >> 1]);
    }
    __syncthreads();
#pragma unroll
    for (int kk = 0; kk < 2; ++kk) {
      short8 af[4], bfr[4];
#pragma unroll
      for (int mi = 0; mi < 4; ++mi) {
        int row = wm + mi * 16 + lr;
        int off = (row << 7) | ((kk * 64 + lh * 16) ^ ((row & 7) << 4));
        af[mi] = *(const short8*)&As[off >> 1];
      }
#pragma unroll
      for (int ni = 0; ni < 4; ++ni) {
        int row = wn + ni * 16 + lr;
        int off = (row << 7) | ((kk * 64 + lh * 16) ^ ((row & 7) << 4));
        bfr[ni] = *(const short8*)&Bs[off >> 1];
      }
#pragma unroll
      for (int mi = 0; mi < 4; ++mi)
#pragma unroll
        for (int ni = 0; ni < 4; ++ni)
          acc[mi][ni] = __builtin_amdgcn_mfma_f32_16x16x32_bf16(
              af[mi], bfr[ni], acc[mi][ni], 0, 0, 0);
    }
    __syncthreads();
  }
#pragma unroll
  for (int mi = 0; mi < 4; ++mi)
#pragma unroll
    for (int ni = 0; ni < 4; ++ni)
#pragma unroll
      for (int r = 0; r < 4; ++r) {
        size_t grow = arow + wm + mi * 16 + lh * 4 + r;
        size_t gcol = brow + wn + ni * 16 + lr;
        float v = acc[mi][ni][r];
        if constexpr (sizeof(CT) == 2)
          ((unsigned short*)C)[grow * N + gcol] = f2bf(v);
        else
          C[grow * N + gcol] = v;
      }
}

// ---------------- fused GQA attention v3: group-shared K/V staging ----------
// block = (kv-group g, 32-row q-tile), 4 waves = the 4 heads of the group.
// Each wave: 2 q-column-tiles (qc) of 16, swapped QK^T (lane owns q=lr),
// permuted-K feeding so P lands in PV B-fragment layout, O^T accumulation,
// descending KV tiles + defer-max. K/V staged ONCE per block for 4 heads.
// g = bid&7 pins each group's K/V (1 MB) to one XCD L2; heavy/light q-tile
// pairing balances the causal triangle (2 blocks/CU co-resident).
__global__ __launch_bounds__(256, 2) void attn_kernel(
    const unsigned short* __restrict__ qkv, const unsigned short* __restrict__ vt,
    const int* __restrict__ pos, unsigned short* __restrict__ aout) {
  __shared__ unsigned short Klds[64 * 128];   // [key][d], swz ((row>>1)&7)<<4
  __shared__ unsigned short Vlds[128 * 64];   // [d][key], swz (row&7)<<4

  int b = blockIdx.x;
  int g = b & 7;                              // group -> XCD
  int rr = b >> 3;                            // 0..63
  int qt = (rr < 32) ? (63 - rr) : (rr - 32); // heavy first, pair heavy+light per CU

  int tid = threadIdx.x, lane = tid & 63, wave = tid >> 6;
  int lr = lane & 15, lh = lane >> 4;
  int h = g * 4 + wave;                       // each wave owns one head

  const float L2E = 1.4426950408889634f;
  float slope2 = exp2f(-0.25f * (float)(h + 1)) * L2E;
  const float QS2 = 0.08838834764831845f * L2E;
  const float THR = 8.0f * L2E;

  int qrow0 = qt * 32;

  short8 qf[2][4];
#pragma unroll
  for (int qc = 0; qc < 2; ++qc)
#pragma unroll
    for (int kk = 0; kk < 4; ++kk)
      qf[qc][kk] = *(const short8*)&qkv[(size_t)(qrow0 + qc * 16 + lr) * OTOT +
                                        h * 128 + kk * 32 + lh * 8];
  int qpos[2] = {pos[qrow0 + lr], pos[qrow0 + 16 + lr]};

  float m_run[2] = {-3.0e38f, -3.0e38f}, l_run[2] = {0.f, 0.f};
  floatx4 acc[8][2];
#pragma unroll
  for (int n = 0; n < 8; ++n)
#pragma unroll
    for (int qc = 0; qc < 2; ++qc) acc[n][qc] = (floatx4){0.f, 0.f, 0.f, 0.f};

  int nkt = (qt >> 1) + 1;
  for (int jj = 0; jj < nkt; ++jj) {
    int j = nkt - 1 - jj;                     // descending: diagonal first
    int kbase = j * 64;
#pragma unroll
    for (int i = 0; i < 4; ++i) {
      int lin = i * 4096 + tid * 16;
      int row = lin >> 8;
      int colb = (lin & 255) ^ (((row >> 1) & 7) << 4);
      gload_lds16(&qkv[(size_t)(kbase + row) * OTOT + KOFF + g * 128 + (colb >> 1)],
                  &Klds[(i * 4096 + wave * 1024) >> 1]);
    }
#pragma unroll
    for (int i = 0; i < 4; ++i) {
      int lin = i * 4096 + tid * 16;
      int row = lin >> 7;
      int colb = (lin & 127) ^ ((row & 7) << 4);
      gload_lds16(&vt[(size_t)(g * 128 + row) * S_LEN + kbase + (colb >> 1)],
                  &Vlds[(i * 4096 + wave * 1024) >> 1]);
    }
    __syncthreads();

    // swapped QK^T: sc[n][qc][r] = S[key=32*(n&1)+8*lh+2*r+(n>>1)][q=qc*16+lr]
    floatx4 sc[4][2];
#pragma unroll
    for (int n = 0; n < 4; ++n)
#pragma unroll
      for (int qc = 0; qc < 2; ++qc) sc[n][qc] = (floatx4){0.f, 0.f, 0.f, 0.f};
    __builtin_amdgcn_s_setprio(1);
#pragma unroll
    for (int n = 0; n < 4; ++n) {
      int rowk = 32 * (n & 1) + 2 * lr + (n >> 1);
      int swz = ((rowk >> 1) & 7) << 4;
#pragma unroll
      for (int kk = 0; kk < 4; ++kk) {
        short8 kf = *(const short8*)&Klds[((rowk << 8) | ((kk * 64 + lh * 16) ^ swz)) >> 1];
        sc[n][0] = __builtin_amdgcn_mfma_f32_16x16x32_bf16(kf, qf[0][kk], sc[n][0], 0, 0, 0);
        sc[n][1] = __builtin_amdgcn_mfma_f32_16x16x32_bf16(kf, qf[1][kk], sc[n][1], 0, 0, 0);
      }
    }
    __builtin_amdgcn_s_setprio(0);

    int4 a0 = *(const int4*)&pos[kbase + lh * 8];
    int4 a1 = *(const int4*)&pos[kbase + lh * 8 + 4];
    int4 b0 = *(const int4*)&pos[kbase + 32 + lh * 8];
    int4 b1 = *(const int4*)&pos[kbase + 32 + lh * 8 + 4];
    int klo[8] = {a0.x, a0.y, a0.z, a0.w, a1.x, a1.y, a1.z, a1.w};
    int khi[8] = {b0.x, b0.y, b0.z, b0.w, b1.x, b1.y, b1.z, b1.w};

    float mx[2] = {-3.0e38f, -3.0e38f};
#pragma unroll
    for (int n = 0; n < 4; ++n)
#pragma unroll
      for (int rj = 0; rj < 4; ++rj) {
        int jidx = 2 * rj + (n >> 1);
        int kp = (n & 1) ? khi[jidx] : klo[jidx];
#pragma unroll
        for (int qc = 0; qc < 2; ++qc) {
          int dist = qpos[qc] - kp;
          float sv = sc[n][qc][rj] * QS2 - slope2 * sqrtf((float)dist);
          sv = (dist < 0) ? -1.0e38f : sv;
          sc[n][qc][rj] = sv;
          mx[qc] = fmaxf(mx[qc], sv);
        }
      }
#pragma unroll
    for (int qc = 0; qc < 2; ++qc) {
      mx[qc] = fmaxf(mx[qc], __shfl_xor(mx[qc], 16));
      mx[qc] = fmaxf(mx[qc], __shfl_xor(mx[qc], 32));
    }

    bool nd = (mx[0] > m_run[0] + THR) | (mx[1] > m_run[1] + THR);
    if (__any(nd)) {
#pragma unroll
      for (int qc = 0; qc < 2; ++qc) {
        float mnew = fmaxf(m_run[qc], mx[qc]);
        float al = exp2f(m_run[qc] - mnew);
        l_run[qc] *= al;
#pragma unroll
        for (int n = 0; n < 8; ++n) acc[n][qc] *= al;
        m_run[qc] = mnew;
      }
    }

    union bfp { unsigned int u[4]; short8 v; };
    bfp pfA0, pfA1, pfB0, pfB1;
    float rs0 = 0.f, rs1 = 0.f;
#pragma unroll
    for (int w = 0; w < 4; ++w) {
      float e0 = exp2f(sc[0][0][w] - m_run[0]);
      float e2 = exp2f(sc[2][0][w] - m_run[0]);
      float e1 = exp2f(sc[1][0][w] - m_run[0]);
      float e3 = exp2f(sc[3][0][w] - m_run[0]);
      rs0 += (e0 + e2) + (e1 + e3);
      pfA0.u[w] = pack2bf(e0, e2);
      pfA1.u[w] = pack2bf(e1, e3);
      float f0 = exp2f(sc[0][1][w] - m_run[1]);
      float f2 = exp2f(sc[2][1][w] - m_run[1]);
      float f1 = exp2f(sc[1][1][w] - m_run[1]);
      float f3 = exp2f(sc[3][1][w] - m_run[1]);
      rs1 += (f0 + f2) + (f1 + f3);
      pfB0.u[w] = pack2bf(f0, f2);
      pfB1.u[w] = pack2bf(f1, f3);
    }
    rs0 += __shfl_xor(rs0, 16); rs0 += __shfl_xor(rs0, 32);
    rs1 += __shfl_xor(rs1, 16); rs1 += __shfl_xor(rs1, 32);
    l_run[0] += rs0;
    l_run[1] += rs1;

    __builtin_amdgcn_s_setprio(1);
#pragma unroll
    for (int n = 0; n < 8; ++n) {
      int rowv = n * 16 + lr;
      int swz = (rowv & 7) << 4;
      short8 v0 = *(const short8*)&Vlds[((rowv << 7) | ((lh * 16) ^ swz)) >> 1];
      short8 v1 = *(const short8*)&Vlds[((rowv << 7) | ((64 + lh * 16) ^ swz)) >> 1];
      acc[n][0] = __builtin_amdgcn_mfma_f32_16x16x32_bf16(v0, pfA0.v, acc[n][0], 0, 0, 0);
      acc[n][0] = __builtin_amdgcn_mfma_f32_16x16x32_bf16(v1, pfA1.v, acc[n][0], 0, 0, 0);
      acc[n][1] = __builtin_amdgcn_mfma_f32_16x16x32_bf16(v0, pfB0.v, acc[n][1], 0, 0, 0);
      acc[n][1] = __builtin_amdgcn_mfma_f32_16x16x32_bf16(v1, pfB1.v, acc[n][1], 0, 0, 0);
    }
    __builtin_amdgcn_s_setprio(0);
    __syncthreads();
  }

#pragma unroll
  for (int qc = 0; qc < 2; ++qc) {
    float inv = 1.0f / l_run[qc];
#pragma unroll
    for (int n = 0; n < 8; ++n) {
      ushort4 o;
      o.x = f2bf(acc[n][qc][0] * inv);
      o.y = f2bf(acc[n][qc][1] * inv);
      o.z = f2bf(acc[n][qc][2] * inv);
      o.w = f2bf(acc[n][qc][3] * inv);
      *(ushort4*)&aout[(size_t)(qrow0 + qc * 16 + lr) * 4096 + h * 128 + n * 16 + lh * 4] = o;
    }
  }
}

extern "C" void kernel_launch(void* const* d_in, const int* in_sizes, int n_in,
                              void* d_out, int out_size, void* d_ws, size_t ws_size,
                              hipStream_t stream) {
  (void)in_sizes; (void)n_in; (void)out_size;
  const int* positions = (const int*)d_in[0];
  const float* hidden = (const float*)d_in[1];
  const float* wqkv = (const float*)d_in[2];
  const float* wo = (const float*)d_in[3];
  float* out = (float*)d_out;

  char* w = (char*)d_ws;
  unsigned short* hbf   = (unsigned short*)(w);
  unsigned short* wqbf  = (unsigned short*)(w + 16777216);
  unsigned short* wobf  = (unsigned short*)(w + 67108864);
  unsigned short* qkv   = (unsigned short*)(w + 100663296);
  unsigned short* vtb   = (unsigned short*)(w + 125829120);
  unsigned short* attnb = (unsigned short*)(w + 130023424);
  if (ws_size < 146800640) return;

  cast3_kernel<<<2048, 256, 0, stream>>>(hidden, wqkv, wo, hbf, wqbf, wobf);
  gemm_bt_kernel<unsigned short><<<768, 256, 0, stream>>>(hbf, wqbf, qkv, 2048, 6144, 4096);
  transpose_v_kernel<<<256, 256, 0, stream>>>(qkv, vtb);
  attn_kernel<<<512, 256, 0, stream>>>(qkv, vtb, positions, attnb);
  gemm_bt_kernel<float><<<512, 256, 0, stream>>>(attnb, wobf, out, 2048, 4096, 4096);
}